// Round 21
// baseline (78.268 us; speedup 1.0000x reference)
//
#include <hip/hip_runtime.h>

// Modulated deformable depthwise conv, B=8 C=128 H=W=64 K=3 PAD=1 STRIDE=1.
// Round 20: round 19 with the compile fix (cvt_pkrtz returns __fp16x2,
// fdot2 wants _Float16x2 -> __builtin_bit_cast). Theory unchanged:
// pair-cell fp16 layout (cell = 4 x half2, one per channel, (colA,colB)),
// dual parity blocks at uniform 37-cell row stride -> any in-window tap =
// exactly 2 ds_read_b128 (rows y0,y0+1), halving LDS instructions and
// conflicts (r15 evidence: conflicts scale with read count, 3.97M->2.40M).
// v_dot2_f32_f16 consumes packed pairs directly: per tap-4ch VALU = 2
// cvt_pkrtz + 8 fdot2 + 4 fma < r13's 20 fma. Structure = round 13
// (CH=16, dbuf 37.9KB -> 4 blocks/CU, 1 barrier/iter, corrective hoist).

typedef _Float16 h2_t __attribute__((ext_vector_type(2)));

#define BB 8
#define CC 128
#define HH 64
#define WW 64
#define HWs (HH*WW)
#define KKT 9
#define CH 16              // channels per block
#define NCG (CC/CH)        // 8
#define CPI 4              // channels per cell
#define NIT (CH/CPI)       // 4
#define ROWS 4
#define NHS (HH/ROWS)      // 16
#define WLO 5
#define WR  (ROWS+12)      // 16 staged rows
#define CLO 5
#define WC  74             // window cols 0..73 (actual -5..68); x0w <= 72
#define WCP 37             // pair-cells per row (both parities, uniform)
#define PCELLS (WR*WCP)    // 592 cells per parity block
#define BUFCELLS (2*PCELLS) // 1184 cells = 18.94 KB per buffer
#define ROWB (WCP*16)      // 592 B row stride
#define ODELTA_B (PCELLS*16) // 9472 B offset of O block
#define NTHR 256
#define NK  ((BUFCELLS + NTHR - 1)/NTHR)   // 5

__global__ __launch_bounds__(NTHR, 2)
void mdcn_kernel(const float* __restrict__ x,
                 const float* __restrict__ offset,
                 const float* __restrict__ mask,
                 const float* __restrict__ dynw,
                 float* __restrict__ out)
{
    __shared__ float4 lds[2][BUFCELLS];   // 37.9 KB

    const int blk = blockIdx.x;
    const int hs = blk & (NHS - 1);
    const int cg = (blk >> 4) & (NCG - 1);
    const int b  = blk >> 7;
    const int tid = threadIdx.x;
    const int w = tid & 63;
    const int h0 = hs * ROWS;
    const int h = h0 + (tid >> 6);

    const float* xg = x + (size_t)(b * CC + cg * CH) * HWs;

    float4 stg[NK];   // each = 4 x half2 (ch0..ch3, (colA,colB))
    #define STAGE_LOAD(XP)                                                    \
    do {                                                                      \
        const float* xp_ = (XP);                                              \
        _Pragma("unroll")                                                     \
        for (int k = 0; k < NK; ++k) {                                        \
            const int idx = tid + k * NTHR;                                   \
            float4 cell = make_float4(0.f, 0.f, 0.f, 0.f);                    \
            if (idx < BUFCELLS) {                                             \
                const int p   = (idx >= PCELLS);                              \
                const int rem = idx - p * PCELLS;                             \
                const int row = rem / WCP;                                    \
                const int j   = rem - row * WCP;                              \
                const int ar  = h0 - WLO + row;                               \
                const int ca  = 2 * j + p - CLO;                              \
                const bool rok = (unsigned)ar < (unsigned)HH;                 \
                const bool aok = rok && (unsigned)ca < (unsigned)WW;          \
                const bool bok = rok && (unsigned)(ca + 1) < (unsigned)WW;    \
                const float* pr = xp_ + ar * WW;                              \
                _Pragma("unroll")                                             \
                for (int c = 0; c < CPI; ++c) {                               \
                    const float fA = aok ? pr[c * HWs + ca]     : 0.f;        \
                    const float fB = bok ? pr[c * HWs + ca + 1] : 0.f;        \
                    h2_t hp; hp.x = (_Float16)fA; hp.y = (_Float16)fB;        \
                    ((h2_t*)&cell)[c] = hp;                                   \
                }                                                             \
            }                                                                 \
            stg[k] = cell;                                                    \
        }                                                                     \
    } while (0)

    #define STAGE_WRITE(DST)                                                  \
    do {                                                                      \
        float4* Lb_ = &lds[DST][0];                                           \
        _Pragma("unroll")                                                     \
        for (int k = 0; k < NK; ++k) {                                        \
            const int idx = tid + k * NTHR;                                   \
            if (idx < BUFCELLS) Lb_[idx] = stg[k];                            \
        }                                                                     \
    } while (0)

    // prologue: stage group 0 into buf0; metadata overlaps load latency
    STAGE_LOAD(xg);

    // ---- per-tap metadata: m, dy, dx + pair-cell byte offset ----
    float mv[KKT], dyv[KKT], dxv[KKT];
    int   woff[KKT];
    int   badmask = 0;
    const float* offp = offset + (size_t)b * (2 * KKT) * HWs + h * WW + w;
    const float* mskp = mask   + (size_t)b * KKT * HWs       + h * WW + w;
    #pragma unroll
    for (int t = 0; t < KKT; ++t) {
        const float oy = offp[(2 * t)     * HWs];
        const float ox = offp[(2 * t + 1) * HWs];
        const float m  = mskp[t * HWs];
        const float py = (float)(h - 1 + t / 3) + oy;
        const float px = (float)(w - 1 + t % 3) + ox;
        const float fy = floorf(py), fx = floorf(px);
        const int y0 = (int)fy, x0 = (int)fx;
        dyv[t] = py - fy;
        dxv[t] = px - fx;
        const bool inwin = (y0 >= h0 - WLO) && (y0 <= h0 - WLO + WR - 2) &&
                           (x0 >= -CLO)     && (x0 <= -CLO + WC - 2);
        if (!inwin) {
            badmask |= (1 << t);
            woff[t] = 0;
            mv[t] = 0.f;               // zeroes the LDS contribution
        } else {
            const int rb  = y0 - (h0 - WLO);
            const int x0w = x0 + CLO;                 // 0..72
            woff[t] = ((x0w & 1) ? ODELTA_B : 0)
                    + (rb * WCP + (x0w >> 1)) * 16;
            mv[t] = m;
        }
    }
    const int anybad = __any(badmask != 0);

    STAGE_WRITE(0);
    __syncthreads();

    const float* wtb  = dynw + (size_t)(b * CC + cg * CH) * KKT;
    float*       outp = out  + (size_t)(b * CC + cg * CH) * HWs + h * WW + w;

    for (int it = 0; it < NIT; ++it) {
        const float* wt = wtb + it * CPI * KKT;
        float s0 = 0.f, s1 = 0.f, s2 = 0.f, s3 = 0.f;

        // corrective path FIRST (stg not yet live; execz-skipped at runtime)
        if (anybad) {
            #pragma unroll
            for (int t = 0; t < KKT; ++t) {
                if (badmask & (1 << t)) {
                    const float oy = offp[(2 * t)     * HWs];
                    const float ox = offp[(2 * t + 1) * HWs];
                    const float m  = mskp[t * HWs];
                    const float py = (float)(h - 1 + t / 3) + oy;
                    const float px = (float)(w - 1 + t % 3) + ox;
                    const float fy = floorf(py), fx = floorf(px);
                    const float dy = py - fy, dx = px - fx;
                    const int y0 = (int)fy, x0 = (int)fx;
                    const int y1 = y0 + 1,  x1 = x0 + 1;
                    const int cy0 = min(max(y0, 0), HH - 1);
                    const int cy1 = min(max(y1, 0), HH - 1);
                    const int cx0 = min(max(x0, 0), WW - 1);
                    const int cx1 = min(max(x1, 0), WW - 1);
                    const float m00 = ((unsigned)y0 < HH && (unsigned)x0 < WW) ? 1.f : 0.f;
                    const float m01 = ((unsigned)y0 < HH && (unsigned)x1 < WW) ? 1.f : 0.f;
                    const float m10 = ((unsigned)y1 < HH && (unsigned)x0 < WW) ? 1.f : 0.f;
                    const float m11 = ((unsigned)y1 < HH && (unsigned)x1 < WW) ? 1.f : 0.f;
                    const float omdy = 1.f - dy, omdx = 1.f - dx;
                    #pragma unroll
                    for (int c = 0; c < CPI; ++c) {
                        const float* pl = xg + (size_t)(it * CPI + c) * HWs;
                        const float v = pl[cy0 * WW + cx0] * m00 * (omdy * omdx)
                                      + pl[cy0 * WW + cx1] * m01 * (omdy * dx)
                                      + pl[cy1 * WW + cx0] * m10 * (dy * omdx)
                                      + pl[cy1 * WW + cx1] * m11 * (dy * dx);
                        const float add = v * m * wt[c * KKT + t];
                        if      (c == 0) s0 += add;
                        else if (c == 1) s1 += add;
                        else if (c == 2) s2 += add;
                        else             s3 += add;
                    }
                }
            }
        }

        // prefetch next group (hidden under the tap loop)
        if (it + 1 < NIT) {
            STAGE_LOAD(xg + (size_t)(it + 1) * CPI * HWs);
        }

        const char* bb = (const char*)&lds[it & 1][0];
        #pragma unroll
        for (int t = 0; t < KKT; ++t) {
            const float4 r0 = *(const float4*)(bb + woff[t]);          // row y0
            const float4 r1 = *(const float4*)(bb + woff[t] + ROWB);   // row y0+1
            const float dy = dyv[t], dx = dxv[t], m = mv[t];
            const float omdy = 1.f - dy, omdx = 1.f - dx;
            const float w00 = omdy * omdx * m, w01 = omdy * dx * m;
            const float w10 = dy * omdx * m,   w11 = dy * dx * m;
            const auto pk0 = __builtin_amdgcn_cvt_pkrtz(w00, w01);
            const auto pk1 = __builtin_amdgcn_cvt_pkrtz(w10, w11);
            const h2_t hw0 = __builtin_bit_cast(h2_t, pk0);
            const h2_t hw1 = __builtin_bit_cast(h2_t, pk1);
            const h2_t* p0 = (const h2_t*)&r0;
            const h2_t* p1 = (const h2_t*)&r1;
            const float v0 = __builtin_amdgcn_fdot2(p0[0], hw0,
                               __builtin_amdgcn_fdot2(p1[0], hw1, 0.f, false), false);
            const float v1 = __builtin_amdgcn_fdot2(p0[1], hw0,
                               __builtin_amdgcn_fdot2(p1[1], hw1, 0.f, false), false);
            const float v2 = __builtin_amdgcn_fdot2(p0[2], hw0,
                               __builtin_amdgcn_fdot2(p1[2], hw1, 0.f, false), false);
            const float v3 = __builtin_amdgcn_fdot2(p0[3], hw0,
                               __builtin_amdgcn_fdot2(p1[3], hw1, 0.f, false), false);
            s0 += v0 * wt[0 * KKT + t];
            s1 += v1 * wt[1 * KKT + t];
            s2 += v2 * wt[2 * KKT + t];
            s3 += v3 * wt[3 * KKT + t];
        }

        // write next group into the IDLE buffer (no pre-barrier needed)
        if (it + 1 < NIT) {
            STAGE_WRITE((it + 1) & 1);
        }

        outp[(size_t)(it * CPI + 0) * HWs] = s0;
        outp[(size_t)(it * CPI + 1) * HWs] = s1;
        outp[(size_t)(it * CPI + 2) * HWs] = s2;
        outp[(size_t)(it * CPI + 3) * HWs] = s3;

        if (it + 1 < NIT) {
            __syncthreads();   // writes visible; old buffer free for reuse
        }
    }
    #undef STAGE_LOAD
    #undef STAGE_WRITE
}

extern "C" void kernel_launch(void* const* d_in, const int* in_sizes, int n_in,
                              void* d_out, int out_size, void* d_ws, size_t ws_size,
                              hipStream_t stream) {
    const float* x      = (const float*)d_in[0];
    const float* offset = (const float*)d_in[1];
    const float* mask   = (const float*)d_in[2];
    const float* dynw   = (const float*)d_in[3];
    float* out = (float*)d_out;

    dim3 grid(BB * NCG * NHS);   // 8 * 8 * 16 = 1024 blocks
    dim3 block(NTHR);
    mdcn_kernel<<<grid, block, 0, stream>>>(x, offset, mask, dynw, out);
}

// Round 22
// 38.496 us; speedup vs baseline: 2.0332x; 2.0332x over previous
//
#include <hip/hip_runtime.h>

// Modulated deformable depthwise conv, B=8 C=128 H=W=64 K=3 PAD=1 STRIDE=1.
// Round 21: one-shot blocks (r18's block-turnover pipelining, stage -> ONE
// barrier -> compute -> exit) at CH=8 (2x metadata vs r13, not r18's 4x).
// LDS = two consecutive r13-style fp32 float4 buffers (A: ch0-3, B: ch4-7,
// same woff) -> tap = 8 ds_read_b128 with 8 independent acc chains (2x ILP
// at fixed wave count). Staging keeps r13's proven coalesced 4-stream-per-
// group pattern (r20's stride-2 parity staging destroyed coalescing).
// stg[10] (~40 regs) dies at the barrier. 37.9KB single buffer -> 4
// blocks/CU; grid 2048 rolling; cg-fastest so 16 consecutive blocks share
// identical metadata (L2 broadcast).

#define BB 8
#define CC 128
#define HH 64
#define WW 64
#define HWs (HH*WW)
#define KKT 9
#define CH 8               // channels per block (2 float4 groups)
#define NCG (CC/CH)        // 16
#define ROWS 4
#define NHS (HH/ROWS)      // 16
#define WLO 5
#define WR  (ROWS+12)      // 16 staged rows
#define CLO 5
#define WC  74             // cols -5 .. 68
#define CELLS (WR*WC)      // 1184 float4 cells per group buffer
#define NTHR 256
#define NK  ((CELLS + NTHR - 1)/NTHR)   // 5

__global__ __launch_bounds__(NTHR, 2)
void mdcn_kernel(const float* __restrict__ x,
                 const float* __restrict__ offset,
                 const float* __restrict__ mask,
                 const float* __restrict__ dynw,
                 float* __restrict__ out)
{
    __shared__ float4 lds[2][CELLS];   // [group][cell]; 37.9 KB

    // cg fastest: 16 consecutive blocks share (b,hs) -> identical metadata
    const int blk = blockIdx.x;
    const int cg = blk & (NCG - 1);
    const int r  = blk >> 4;
    const int hs = r & (NHS - 1);
    const int b  = r >> 4;
    const int tid = threadIdx.x;
    const int w = tid & 63;
    const int h0 = hs * ROWS;
    const int h = h0 + (tid >> 6);

    const float* xg = x + (size_t)(b * CC + cg * CH) * HWs;

    // ---- issue staging loads for both groups (coalesced per-plane) ----
    float4 stgA[NK], stgB[NK];
    #pragma unroll
    for (int k = 0; k < NK; ++k) {
        const int idx = tid + k * NTHR;
        float4 vA = make_float4(0.f, 0.f, 0.f, 0.f);
        float4 vB = make_float4(0.f, 0.f, 0.f, 0.f);
        if (idx < CELLS) {
            const int row = idx / WC;
            const int col = idx - row * WC - CLO;
            const int ar  = h0 - WLO + row;
            if ((unsigned)ar < (unsigned)HH && (unsigned)col < (unsigned)WW) {
                const float* pp = xg + ar * WW + col;
                vA.x = pp[0 * HWs]; vA.y = pp[1 * HWs];
                vA.z = pp[2 * HWs]; vA.w = pp[3 * HWs];
                vB.x = pp[4 * HWs]; vB.y = pp[5 * HWs];
                vB.z = pp[6 * HWs]; vB.w = pp[7 * HWs];
            }
        }
        stgA[k] = vA;
        stgB[k] = vB;
    }

    // ---- per-tap metadata (overlaps load latency) ----
    float mv[KKT], dyv[KKT], dxv[KKT];
    int   woff[KKT];
    int   badmask = 0;
    const float* offp = offset + (size_t)b * (2 * KKT) * HWs + h * WW + w;
    const float* mskp = mask   + (size_t)b * KKT * HWs       + h * WW + w;
    #pragma unroll
    for (int t = 0; t < KKT; ++t) {
        const float oy = offp[(2 * t)     * HWs];
        const float ox = offp[(2 * t + 1) * HWs];
        const float m  = mskp[t * HWs];
        const float py = (float)(h - 1 + t / 3) + oy;
        const float px = (float)(w - 1 + t % 3) + ox;
        const float fy = floorf(py), fx = floorf(px);
        const int y0 = (int)fy, x0 = (int)fx;
        dyv[t] = py - fy;
        dxv[t] = px - fx;
        const bool inwin = (y0 >= h0 - WLO) && (y0 <= h0 - WLO + WR - 2) &&
                           (x0 >= -CLO)     && (x0 <= -CLO + WC - 2);
        if (!inwin) {
            badmask |= (1 << t);
            woff[t] = 0;
            mv[t] = 0.f;               // zeroes the LDS contribution
        } else {
            woff[t] = (y0 - (h0 - WLO)) * WC + (x0 + CLO);
            mv[t] = m;                 // pads hold zeros -> no corner masks
        }
    }
    const int anybad = __any(badmask != 0);

    const float* wt   = dynw + (size_t)(b * CC + cg * CH) * KKT;
    float*       outp = out  + (size_t)(b * CC + cg * CH) * HWs + h * WW + w;

    float s0 = 0.f, s1 = 0.f, s2 = 0.f, s3 = 0.f;
    float s4 = 0.f, s5 = 0.f, s6 = 0.f, s7 = 0.f;

    // rare corrective path (exact, from global; overlaps load latency)
    if (anybad) {
        #pragma unroll
        for (int t = 0; t < KKT; ++t) {
            if (badmask & (1 << t)) {
                const float oy = offp[(2 * t)     * HWs];
                const float ox = offp[(2 * t + 1) * HWs];
                const float m  = mskp[t * HWs];
                const float py = (float)(h - 1 + t / 3) + oy;
                const float px = (float)(w - 1 + t % 3) + ox;
                const float fy = floorf(py), fx = floorf(px);
                const float dy = py - fy, dx = px - fx;
                const int y0 = (int)fy, x0 = (int)fx;
                const int y1 = y0 + 1,  x1 = x0 + 1;
                const int cy0 = min(max(y0, 0), HH - 1);
                const int cy1 = min(max(y1, 0), HH - 1);
                const int cx0 = min(max(x0, 0), WW - 1);
                const int cx1 = min(max(x1, 0), WW - 1);
                const float m00 = ((unsigned)y0 < HH && (unsigned)x0 < WW) ? 1.f : 0.f;
                const float m01 = ((unsigned)y0 < HH && (unsigned)x1 < WW) ? 1.f : 0.f;
                const float m10 = ((unsigned)y1 < HH && (unsigned)x0 < WW) ? 1.f : 0.f;
                const float m11 = ((unsigned)y1 < HH && (unsigned)x1 < WW) ? 1.f : 0.f;
                const float omdy = 1.f - dy, omdx = 1.f - dx;
                #pragma unroll
                for (int c = 0; c < CH; ++c) {
                    const float* pl = xg + (size_t)c * HWs;
                    const float v = pl[cy0 * WW + cx0] * m00 * (omdy * omdx)
                                  + pl[cy0 * WW + cx1] * m01 * (omdy * dx)
                                  + pl[cy1 * WW + cx0] * m10 * (dy * omdx)
                                  + pl[cy1 * WW + cx1] * m11 * (dy * dx);
                    const float add = v * m * wt[c * KKT + t];
                    if      (c == 0) s0 += add;
                    else if (c == 1) s1 += add;
                    else if (c == 2) s2 += add;
                    else if (c == 3) s3 += add;
                    else if (c == 4) s4 += add;
                    else if (c == 5) s5 += add;
                    else if (c == 6) s6 += add;
                    else             s7 += add;
                }
            }
        }
    }

    // ---- write both groups to LDS (vmcnt drains here), one barrier ----
    #pragma unroll
    for (int k = 0; k < NK; ++k) {
        const int idx = tid + k * NTHR;
        if (idx < CELLS) {
            lds[0][idx] = stgA[k];
            lds[1][idx] = stgB[k];
        }
    }
    __syncthreads();

    // ---- tap loop: 8 ds_read_b128 per tap, 8 independent acc chains ----
    #pragma unroll
    for (int t = 0; t < KKT; ++t) {
        const float dy = dyv[t], dx = dxv[t], m = mv[t];
        const float omdy = 1.f - dy, omdx = 1.f - dx;
        const float w00 = omdy * omdx * m, w01 = omdy * dx * m;
        const float w10 = dy * omdx * m,   w11 = dy * dx * m;

        const float4 a00 = lds[0][woff[t]];
        const float4 a01 = lds[0][woff[t] + 1];
        const float4 a10 = lds[0][woff[t] + WC];
        const float4 a11 = lds[0][woff[t] + WC + 1];
        const float4 b00 = lds[1][woff[t]];
        const float4 b01 = lds[1][woff[t] + 1];
        const float4 b10 = lds[1][woff[t] + WC];
        const float4 b11 = lds[1][woff[t] + WC + 1];

        const float vA0 = a00.x * w00 + a01.x * w01 + a10.x * w10 + a11.x * w11;
        const float vA1 = a00.y * w00 + a01.y * w01 + a10.y * w10 + a11.y * w11;
        const float vA2 = a00.z * w00 + a01.z * w01 + a10.z * w10 + a11.z * w11;
        const float vA3 = a00.w * w00 + a01.w * w01 + a10.w * w10 + a11.w * w11;
        const float vB0 = b00.x * w00 + b01.x * w01 + b10.x * w10 + b11.x * w11;
        const float vB1 = b00.y * w00 + b01.y * w01 + b10.y * w10 + b11.y * w11;
        const float vB2 = b00.z * w00 + b01.z * w01 + b10.z * w10 + b11.z * w11;
        const float vB3 = b00.w * w00 + b01.w * w01 + b10.w * w10 + b11.w * w11;

        s0 += vA0 * wt[0 * KKT + t];
        s1 += vA1 * wt[1 * KKT + t];
        s2 += vA2 * wt[2 * KKT + t];
        s3 += vA3 * wt[3 * KKT + t];
        s4 += vB0 * wt[4 * KKT + t];
        s5 += vB1 * wt[5 * KKT + t];
        s6 += vB2 * wt[6 * KKT + t];
        s7 += vB3 * wt[7 * KKT + t];
    }

    outp[0 * HWs] = s0;
    outp[1 * HWs] = s1;
    outp[2 * HWs] = s2;
    outp[3 * HWs] = s3;
    outp[4 * HWs] = s4;
    outp[5 * HWs] = s5;
    outp[6 * HWs] = s6;
    outp[7 * HWs] = s7;
}

extern "C" void kernel_launch(void* const* d_in, const int* in_sizes, int n_in,
                              void* d_out, int out_size, void* d_ws, size_t ws_size,
                              hipStream_t stream) {
    const float* x      = (const float*)d_in[0];
    const float* offset = (const float*)d_in[1];
    const float* mask   = (const float*)d_in[2];
    const float* dynw   = (const float*)d_in[3];
    float* out = (float*)d_out;

    dim3 grid(BB * NCG * NHS);   // 8 * 16 * 16 = 2048 blocks
    dim3 block(NTHR);
    mdcn_kernel<<<grid, block, 0, stream>>>(x, offset, mask, dynw, out);
}